// Round 1
// baseline (317.821 us; speedup 1.0000x reference)
//
#include <hip/hip_runtime.h>
#include <stdint.h>

#define TT 512
#define BB 1024
#define NN 64

__device__ __forceinline__ float lane_bc(float v, int l) {
    // broadcast lane l's value to all lanes via v_readlane (SGPR result)
    return __uint_as_float(__builtin_amdgcn_readlane(__float_as_uint(v), l));
}

// Detect input integer widths (harness may canonicalize int64->int32, bool->int32).
// target int64 <=> high 32-bit words of first 128 elements are all zero
//   (if int32, those words are random tags in [0,64): P(all zero) = 64^-128 ~ 0).
// mask int32  <=> bytes 4i+1..4i+3 are zero (if uint8 bool, row 0 is all-true = 1
//   since lengths >= 1, so those bytes would be 1).
__global__ void __launch_bounds__(64, 1)
detect_kernel(const uint32_t* __restrict__ tgt, const uint8_t* __restrict__ msk,
              int* __restrict__ flags) {
    if (threadIdx.x == 0) {
        uint32_t s = 0;
        for (int i = 0; i < 128; ++i) s |= tgt[2 * i + 1];
        flags[0] = (s == 0) ? 1 : 0;
        uint32_t mz = 0;
        for (int i = 0; i < 8; ++i) mz |= msk[4*i+1] | msk[4*i+2] | msk[4*i+3];
        flags[1] = (mz == 0) ? 1 : 0;
    }
}

__global__ void __launch_bounds__(256, 1)
crf_kernel(const float* __restrict__ emit, const float* __restrict__ trans,
           const float* __restrict__ strans, const float* __restrict__ etrans,
           const void* __restrict__ target, const void* __restrict__ mask,
           const int* __restrict__ flags, float* __restrict__ out)
{
    __shared__ float s_trans[NN * NN];
    const int lane = threadIdx.x & 63;
    const int wid  = threadIdx.x >> 6;
    const int b    = (blockIdx.x << 2) + wid;   // one wave per chain, 256 blocks x 4 waves = 1024

    for (int i = threadIdx.x; i < NN * NN; i += 256) s_trans[i] = trans[i];
    __syncthreads();

    const int t64 = flags[0];
    const int m32 = flags[1];

    // ---- length of chain b: sum of mask[:, b] (contiguous prefix) ----
    int len = 0;
    if (m32) {
        const int32_t* mp = (const int32_t*)mask;
        #pragma unroll
        for (int i = 0; i < TT / 64; ++i)
            len += (mp[(size_t)(i * 64 + lane) * BB + b] != 0) ? 1 : 0;
    } else {
        const uint8_t* mp = (const uint8_t*)mask;
        #pragma unroll
        for (int i = 0; i < TT / 64; ++i)
            len += (mp[(size_t)(i * 64 + lane) * BB + b] != 0) ? 1 : 0;
    }
    #pragma unroll
    for (int off = 32; off; off >>= 1) len += __shfl_xor(len, off);

    // ---- E column k: E[j] = exp(trans[j][k]), kept in 64 VGPRs ----
    float Ecol[NN];
    #pragma unroll
    for (int j = 0; j < NN; ++j) Ecol[j] = __expf(s_trans[j * NN + lane]);

    auto get_tag = [&](int t) -> int {
        if (t64) return (int)((const int64_t*)target)[(size_t)t * BB + b];
        else     return ((const int32_t*)target)[(size_t)t * BB + b];
    };

    // ---- init t = 0 ----
    float e0     = emit[((size_t)0 * BB + b) * NN + lane];
    float alpha0 = strans[lane] + e0;
    float a      = __expf(alpha0);   // linear-space state, carried scale m (log)
    float m      = 0.0f;
    int   tagp   = get_tag(0);
    float score  = __shfl(alpha0, tagp);   // strans[tag0] + emit[0,b,tag0]

    // exact power-of-2 renormalization: a *= 2^-ex, m += ex*ln2
    auto normalize = [&]() {
        float mx = a;
        #pragma unroll
        for (int off = 32; off; off >>= 1) mx = fmaxf(mx, __shfl_xor(mx, off));
        int ex = (int)((__float_as_uint(mx) >> 23) & 0xffu) - 126;
        a = ldexpf(a, -ex);
        m += (float)ex * 0.6931471805599453f;
    };
    normalize();

    // ---- main scan: t = 1 .. len-1 (early exit == contiguous-prefix mask) ----
    float e_nx   = emit[((size_t)1 * BB + b) * NN + lane];
    int   tag_nx = get_tag(1);
    int   cnt    = 0;
    for (int t = 1; t < len; ++t) {
        float ec = e_nx;
        int   tg = tag_nx;
        int   tn = (t + 1 < TT) ? (t + 1) : (TT - 1);
        e_nx   = emit[((size_t)tn * BB + b) * NN + lane];   // prefetch next step
        tag_nx = get_tag(tn);

        // u_k = sum_j a_j * E[j][k]  (readlane broadcast + FMA, 4 accumulators)
        float u0 = 0.f, u1 = 0.f, u2 = 0.f, u3 = 0.f;
        #pragma unroll
        for (int j = 0; j < NN; j += 4) {
            u0 = __builtin_fmaf(lane_bc(a, j + 0), Ecol[j + 0], u0);
            u1 = __builtin_fmaf(lane_bc(a, j + 1), Ecol[j + 1], u1);
            u2 = __builtin_fmaf(lane_bc(a, j + 2), Ecol[j + 2], u2);
            u3 = __builtin_fmaf(lane_bc(a, j + 3), Ecol[j + 3], u3);
        }
        float u = (u0 + u1) + (u2 + u3);
        a = u * __expf(ec);                      // fold in emission (linear space)

        // gold-path score: emit[t,b,tg] + trans[tagp, tg]
        score += __shfl(ec, tg) + s_trans[tagp * NN + tg];
        tagp = tg;

        if ((++cnt & 3) == 0) normalize();       // every 4 steps (range-safe)
    }

    // ---- finalize: logZ_b = m + log(sum_k a_k * exp(etrans_k)) ----
    float v = a * __expf(etrans[lane]);
    #pragma unroll
    for (int off = 32; off; off >>= 1) v += __shfl_xor(v, off);
    float logZ = m + __logf(v);
    score += etrans[tagp];                       // end transition of last valid tag

    if (lane == 0) atomicAdd(out, (logZ - score) * (1.0f / (float)BB));
}

extern "C" void kernel_launch(void* const* d_in, const int* in_sizes, int n_in,
                              void* d_out, int out_size, void* d_ws, size_t ws_size,
                              hipStream_t stream) {
    const float* emit   = (const float*)d_in[0];
    const float* trans  = (const float*)d_in[1];
    const float* strans = (const float*)d_in[2];
    const float* etrans = (const float*)d_in[3];
    const void*  target = d_in[4];
    const void*  mask   = d_in[5];
    int* flags = (int*)d_ws;

    hipMemsetAsync(d_out, 0, sizeof(float), stream);
    detect_kernel<<<1, 64, 0, stream>>>((const uint32_t*)target,
                                        (const uint8_t*)mask, flags);
    crf_kernel<<<256, 256, 0, stream>>>(emit, trans, strans, etrans,
                                        target, mask, flags, (float*)d_out);
}

// Round 2
// 189.389 us; speedup vs baseline: 1.6781x; 1.6781x over previous
//
#include <hip/hip_runtime.h>
#include <stdint.h>

#define TT 512
#define BB 1024
#define NN 64

__device__ __forceinline__ float lane_bc(float v, int l) {
    // broadcast lane l's value to all lanes via v_readlane (SGPR result)
    return __uint_as_float(__builtin_amdgcn_readlane(__float_as_uint(v), l));
}

// Detect input integer widths (harness may canonicalize int64->int32, bool->int32).
__global__ void __launch_bounds__(64, 1)
detect_kernel(const uint32_t* __restrict__ tgt, const uint8_t* __restrict__ msk,
              int* __restrict__ flags) {
    if (threadIdx.x == 0) {
        uint32_t s = 0;
        for (int i = 0; i < 128; ++i) s |= tgt[2 * i + 1];
        flags[0] = (s == 0) ? 1 : 0;   // 1 => target is int64
        uint32_t mz = 0;
        for (int i = 0; i < 8; ++i) mz |= msk[4*i+1] | msk[4*i+2] | msk[4*i+3];
        flags[1] = (mz == 0) ? 1 : 0;  // 1 => mask is int32
    }
}

__global__ void __launch_bounds__(256, 1)
crf_kernel(const float* __restrict__ emit, const float* __restrict__ trans,
           const float* __restrict__ strans, const float* __restrict__ etrans,
           const void* __restrict__ target, const void* __restrict__ mask,
           const int* __restrict__ flags, float* __restrict__ out)
{
    __shared__ float s_trans[NN * NN];
    const int lane = threadIdx.x & 63;
    const int wid  = threadIdx.x >> 6;
    const int b    = (blockIdx.x << 2) + wid;   // one wave per chain

    for (int i = threadIdx.x; i < NN * NN; i += 256) s_trans[i] = trans[i];
    __syncthreads();

    const int t64 = flags[0];
    const int m32 = flags[1];

    // ---- length of chain b: popcount of contiguous-prefix mask[:, b] ----
    int len = 0;
    if (m32) {
        const int32_t* mp = (const int32_t*)mask;
        #pragma unroll
        for (int i = 0; i < TT / 64; ++i)
            len += (mp[(size_t)(i * 64 + lane) * BB + b] != 0) ? 1 : 0;
    } else {
        const uint8_t* mp = (const uint8_t*)mask;
        #pragma unroll
        for (int i = 0; i < TT / 64; ++i)
            len += (mp[(size_t)(i * 64 + lane) * BB + b] != 0) ? 1 : 0;
    }
    #pragma unroll
    for (int off = 32; off; off >>= 1) len += __shfl_xor(len, off);

    // ---- E column (lane = dest state k): E[j] = exp(trans[j][k]) ----
    float Ecol[NN];
    #pragma unroll
    for (int j = 0; j < NN; ++j) Ecol[j] = __expf(s_trans[j * NN + lane]);
    // pin into VGPRs: block rematerialization/spill (R1 showed VGPR=48 => not resident)
    #pragma unroll
    for (int j = 0; j < NN; ++j) asm volatile("" : "+v"(Ecol[j]));

    auto get_tag = [&](int t) -> int {
        if (t64) return (int)((const int64_t*)target)[(size_t)t * BB + b];
        else     return ((const int32_t*)target)[(size_t)t * BB + b];
    };
    auto ld_e = [&](int t) -> float {
        int tc = (t < TT) ? t : (TT - 1);
        return emit[((size_t)tc * BB + b) * NN + lane];
    };
    auto ld_g = [&](int t) -> int {
        int tc = (t < TT) ? t : (TT - 1);
        return get_tag(tc);
    };

    // ---- init t = 0 ----
    float e0     = ld_e(0);
    float alpha0 = strans[lane] + e0;
    float a      = __expf(alpha0);   // linear-space state; carried log-scale m
    float m      = 0.0f;
    int   tagp   = get_tag(0);
    float score  = __shfl(alpha0, tagp);

    // uniform power-of-2 rescale keyed on lane-0 exponent (no cross-lane reduce;
    // spread across lanes after one matvec+emission mix is <= ~2^20, growth/step
    // <= ~2^17, so a 4-step cadence stays well inside fp32 range)
    auto renorm = [&]() {
        float a0 = lane_bc(a, 0);
        int ex = (int)((__float_as_uint(a0) >> 23) & 0xffu) - 127;
        a = ldexpf(a, -ex);
        m += (float)ex * 0.6931471805599453f;
    };
    renorm();

    auto step = [&](float ec, int tg) {
        float eexp = __expf(ec);                 // independent of matvec chain
        float sc_e = __shfl(ec, tg);             // emit[t,b,tg] (off critical path)
        float sc_t = s_trans[tagp * NN + tg];    // trans[tag_{t-1}, tag_t]
        float u0 = 0.f, u1 = 0.f, u2 = 0.f, u3 = 0.f;
        #pragma unroll
        for (int j = 0; j < NN; j += 4) {
            u0 = __builtin_fmaf(lane_bc(a, j + 0), Ecol[j + 0], u0);
            u1 = __builtin_fmaf(lane_bc(a, j + 1), Ecol[j + 1], u1);
            u2 = __builtin_fmaf(lane_bc(a, j + 2), Ecol[j + 2], u2);
            u3 = __builtin_fmaf(lane_bc(a, j + 3), Ecol[j + 3], u3);
        }
        a = ((u0 + u1) + (u2 + u3)) * eexp;
        score += sc_e + sc_t;
        tagp = tg;
    };

    // ---- main scan, unrolled by 4 with depth-4 emit/tag prefetch ----
    int   t  = 1;
    float eA = ld_e(1), eB = ld_e(2), eC = ld_e(3), eD = ld_e(4);
    int   gA = ld_g(1), gB = ld_g(2), gC = ld_g(3), gD = ld_g(4);

    while (t + 4 <= len) {
        float nA = ld_e(t + 4), nB = ld_e(t + 5), nC = ld_e(t + 6), nD = ld_e(t + 7);
        int   hA = ld_g(t + 4), hB = ld_g(t + 5), hC = ld_g(t + 6), hD = ld_g(t + 7);
        step(eA, gA); step(eB, gB); step(eC, gC); step(eD, gD);
        renorm();
        eA = nA; eB = nB; eC = nC; eD = nD;
        gA = hA; gB = hB; gC = hC; gD = hD;
        t += 4;
    }
    if (t < len) { step(eA, gA); ++t; }
    if (t < len) { step(eB, gB); ++t; }
    if (t < len) { step(eC, gC); ++t; }

    // ---- finalize: logZ_b = m + log(sum_k a_k * exp(etrans_k)) ----
    float v = a * __expf(etrans[lane]);
    #pragma unroll
    for (int off = 32; off; off >>= 1) v += __shfl_xor(v, off);
    float logZ = m + __logf(v);
    score += etrans[tagp];

    if (lane == 0) atomicAdd(out, (logZ - score) * (1.0f / (float)BB));
}

extern "C" void kernel_launch(void* const* d_in, const int* in_sizes, int n_in,
                              void* d_out, int out_size, void* d_ws, size_t ws_size,
                              hipStream_t stream) {
    const float* emit   = (const float*)d_in[0];
    const float* trans  = (const float*)d_in[1];
    const float* strans = (const float*)d_in[2];
    const float* etrans = (const float*)d_in[3];
    const void*  target = d_in[4];
    const void*  mask   = d_in[5];
    int* flags = (int*)d_ws;

    hipMemsetAsync(d_out, 0, sizeof(float), stream);
    detect_kernel<<<1, 64, 0, stream>>>((const uint32_t*)target,
                                        (const uint8_t*)mask, flags);
    crf_kernel<<<256, 256, 0, stream>>>(emit, trans, strans, etrans,
                                        target, mask, flags, (float*)d_out);
}